// Round 10
// baseline (412.714 us; speedup 1.0000x reference)
//
#include <hip/hip_runtime.h>
#include <hip/hip_bf16.h>
#include <stdint.h>

// WindowMSA, round 10: two structural fusions.
//  - qkv_kernel: qgemm+kvgemm fused. 256-thr blocks, M=64 rows, SIX half-W
//    phases (96 output rows staged = 36KB LDS) -> 4 blocks/CU for latency
//    hiding. x and skip each read once. acc[6] per phase.
//  - attn_kernel: proj fused in. After the O tile lands in LDS, each wave
//    computes a 16-row x 96-col slice of O@Wproj^T+b (A from LDS O tile,
//    B streamed from L2-hot wproj) and stores f32 directly. No O round-trip.
// attn QK^T/softmax/PV identical to round 9 (double-swapped MFMA).

typedef __bf16 bf16;
typedef __attribute__((ext_vector_type(8))) __bf16 bf16x8;
typedef __attribute__((ext_vector_type(4))) float f32x4;

#define CDIM 192
#define NH 6
#define NTOK 49
#define QSCALE 0.17677669529663687f

// ws byte offsets
#define WSB_W      0u          // 147456 bf16 = 294912 B (wqkv | wskip | wproj)
#define WSE_WSKIP  73728u
#define WSE_WPROJ  110592u
#define WSB_B5     294912u     // b5L: 64*6*16*256 bf16 = 3,145,728 B
#define WSB_QO     3440640u    // 200704*192 bf16 (Q; read-only in attn now)
#define WSB_K      80510976u
#define WSB_V      157581312u  // end 234,651,648

// qkv kernel LDS: 96-row W stage (36864 B), transpose tile reuses first 13312 B
#define QKV_LDS  36864u
#define QTSTRIDE 208u

// attn LDS: VT region 27904 (voff(191)+128 = 27808), 8 strips of 2304
#define OFF_STRIP 27904u
#define STRIPB    2304u
#define ATTN_LDS  46336u       // 27904 + 8*2304
#define OSTRIDE   400u         // O tile row stride (reuses VT region)

__device__ __forceinline__ uint32_t swz384(uint32_t row, uint32_t b) {
  return row * 384u + (b ^ ((row & 7u) << 4));
}
__device__ __forceinline__ uint32_t voff(uint32_t ch) {   // VT row base, 16B-aligned, monotone
  return ch * 144u + ((ch >> 4) << 4);
}
__device__ __forceinline__ uint32_t f2u(float f) { bf16 h = (bf16)f; return (uint32_t)__builtin_bit_cast(uint16_t, h); }
__device__ __forceinline__ bf16x8 lda8(const float* p) {
  float4 w0 = *(const float4*)p;
  float4 w1 = *(const float4*)(p + 4);
  bf16x8 b = {(bf16)w0.x, (bf16)w0.y, (bf16)w0.z, (bf16)w0.w,
              (bf16)w1.x, (bf16)w1.y, (bf16)w1.z, (bf16)w1.w};
  return b;
}
__device__ __forceinline__ float bfu2f(uint32_t lo16) { return __builtin_bit_cast(float, lo16 << 16); }
__device__ __forceinline__ float bfh2f(uint32_t hi16) { return __builtin_bit_cast(float, hi16 & 0xffff0000u); }

// ---- weights f32 -> bf16 ----
__global__ void __launch_bounds__(256)
wcvt_kernel(const float* __restrict__ wqkv, const float* __restrict__ wskip,
            const float* __restrict__ wproj, bf16* __restrict__ ws) {
  uint32_t i = (blockIdx.x * 256u + threadIdx.x) * 4u;
  float4 v;
  if (i < 73728u)       v = *(const float4*)(wqkv + i);
  else if (i < 110592u) v = *(const float4*)(wskip + (i - 73728u));
  else                  v = *(const float4*)(wproj + (i - 110592u));
  *(uint2*)(ws + i) = make_uint2((f2u(v.y) << 16) | f2u(v.x), (f2u(v.w) << 16) | f2u(v.z));
}

// ---- bias for transposed S: t = (((w*6+h)*16 + st*4+nt)*64 + lane)*4 + r
//      i (query) = st*16 + (lane&15) ; j (key) = nt*16 + (lane>>4)*4 + r ----
__global__ void __launch_bounds__(256)
biasprep_kernel(const int* __restrict__ rpi, const float* __restrict__ rpb,
                const float* __restrict__ mask, bf16* __restrict__ b5) {
  uint32_t t = blockIdx.x * 256u + threadIdx.x;
  if (t >= 1572864u) return;
  uint32_t w    = t / 24576u;
  uint32_t rem  = t - w * 24576u;
  uint32_t h    = rem / 4096u;
  uint32_t rem2 = rem & 4095u;
  uint32_t stnt = rem2 >> 8, lane = (rem2 >> 2) & 63u, r = rem2 & 3u;
  uint32_t i = (stnt >> 2) * 16u + (lane & 15u);
  uint32_t j = (stnt & 3u) * 16u + (lane >> 4) * 4u + r;
  float v;
  if (j >= NTOK)      v = -1e30f;      // key-pad: softmax weight -> 0
  else if (i >= NTOK) v = 0.f;         // query-pad rows are never stored
  else v = rpb[(uint32_t)rpi[i * NTOK + j] * NH + h] + mask[(size_t)w * (NTOK * NTOK) + i * NTOK + j];
  b5[t] = (bf16)v;
}

// ---- fused QKV GEMM: 6 half-W phases, M=64/block, 256 thr ----
__global__ void __launch_bounds__(256, 4)
qkv_kernel(const float* __restrict__ skip, const float* __restrict__ x,
           const bf16* __restrict__ wbf, const float* __restrict__ bskip,
           const float* __restrict__ bqkv, bf16* __restrict__ qo,
           bf16* __restrict__ kbf, bf16* __restrict__ vbf) {
  extern __shared__ char lds[];
  const uint32_t tid = threadIdx.x, lane = tid & 63u, wv = tid >> 6;  // 4 waves
  const uint32_t l15 = lane & 15u, lg = lane >> 4;
  const uint32_t rowbase = blockIdx.x * 64u;
  const uint32_t arow = rowbase + wv * 16u + l15;

  bf16x8 af[6];
  #pragma unroll
  for (uint32_t p = 0; p < 6u; ++p) {
    if (p == 0u || p == 2u) {
      const float* ap = (p ? x : skip) + (size_t)arow * CDIM + lg * 8u;
      #pragma unroll
      for (uint32_t kk = 0; kk < 6u; ++kk) af[kk] = lda8(ap + kk * 32u);
    }
    if (p) __syncthreads();            // previous copy-out done
    // stage 96 W rows, swizzled
    const bf16* wsrc = wbf + (p < 2u ? WSE_WSKIP + (p & 1u) * 18432u
                                     : (p - 2u) * 18432u);
    for (uint32_t u = tid; u < 2304u; u += 256u) {       // 96 rows x 24 uint4
      uint32_t row = u / 24u, c16 = u - row * 24u;
      uint4 v = *(const uint4*)(wsrc + row * 192u + c16 * 8u);
      *(uint4*)(lds + row * 384u + ((c16 * 16u) ^ ((row & 7u) << 4))) = v;
    }
    __syncthreads();
    f32x4 acc[6] = {};
    #pragma unroll
    for (uint32_t kk = 0; kk < 6u; ++kk)
      #pragma unroll
      for (uint32_t ntl = 0; ntl < 6u; ++ntl) {
        bf16x8 wb = *(const bf16x8*)(lds + swz384(ntl * 16u + l15, kk * 64u + lg * 16u));
        acc[ntl] = __builtin_amdgcn_mfma_f32_16x16x32_bf16(af[kk], wb, acc[ntl], 0, 0, 0);
      }
    __syncthreads();                   // W reads done -> reuse as transpose tile
    const float* bias_base = (p < 2u) ? bskip + (p & 1u) * 96u
                                      : bqkv + (p - 2u) * 96u;
    const float scale = (p < 2u) ? QSCALE : 1.0f;
    #pragma unroll
    for (uint32_t ntl = 0; ntl < 6u; ++ntl) {
      float bias = bias_base[ntl * 16u + l15];
      #pragma unroll
      for (uint32_t r = 0; r < 4u; ++r) {
        uint32_t trow = wv * 16u + lg * 4u + r;
        *(bf16*)(lds + trow * QTSTRIDE + (ntl * 16u + l15) * 2u) =
            (bf16)((acc[ntl][r] + bias) * scale);
      }
    }
    __syncthreads();                   // transpose tile ready
    bf16* dst = (p < 2u) ? qo : ((p < 4u) ? kbf : vbf);
    const uint32_t colofs = (p & 1u) * 96u;
    for (uint32_t i = tid; i < 768u; i += 256u) {        // 64 rows x 12 uint4
      uint32_t row = i / 12u, c16 = i - row * 12u;
      uint4 v = *(const uint4*)(lds + row * QTSTRIDE + c16 * 16u);
      *(uint4*)(dst + (size_t)(rowbase + row) * CDIM + colofs + c16 * 8u) = v;
    }
  }
}

// ---- attention + proj: one block per window, 512 thr ----
__global__ void __launch_bounds__(512, 6)
attn_kernel(const bf16* __restrict__ qo, const bf16* __restrict__ kbf,
            const bf16* __restrict__ vbf, const bf16* __restrict__ b5L,
            const bf16* __restrict__ wproj_bf, const float* __restrict__ bproj,
            float* __restrict__ out) {
  extern __shared__ char lds[];
  const uint32_t tid = threadIdx.x, lane = tid & 63u, wv = tid >> 6;
  const uint32_t l15 = lane & 15u, lg = lane >> 4;
  const uint32_t grp = wv >> 2, st = wv & 3u;
  const uint32_t win = blockIdx.x;
  char* strip = lds + OFF_STRIP + wv * STRIPB;
  const size_t wrow0 = (size_t)win * NTOK;

  // ---- stage V transposed, tok-pair packed b32 writes ----
  for (uint32_t i = tid; i < 600u; i += 512u) {          // 25 pairs x 24 c16
    uint32_t pair = i / 24u, c16 = i - pair * 24u;
    uint32_t tok0 = pair * 2u;                           // 0,2,..,48
    const bf16* src = vbf + (wrow0 + tok0) * CDIM + c16 * 8u;
    uint4 a = *(const uint4*)src;
    uint4 b = make_uint4(0u, 0u, 0u, 0u);
    if (tok0 + 1u < NTOK) b = *(const uint4*)(src + CDIM);
    uint32_t base = voff(c16 * 8u) + tok0 * 2u;
    uint32_t aw[4] = {a.x, a.y, a.z, a.w};
    uint32_t bw[4] = {b.x, b.y, b.z, b.w};
    #pragma unroll
    for (uint32_t q = 0; q < 4u; ++q) {
      *(uint32_t*)(lds + base + (2u * q) * 144u)      = (aw[q] & 0xffffu) | (bw[q] << 16);
      *(uint32_t*)(lds + base + (2u * q + 1u) * 144u) = (aw[q] >> 16) | (bw[q] & 0xffff0000u);
    }
  }
  for (uint32_t i = tid; i < 1344u; i += 512u) {         // zero toks 50..63
    uint32_t ch = i / 7u, p = i - ch * 7u;
    *(uint32_t*)(lds + voff(ch) + (50u + p * 2u) * 2u) = 0u;
  }
  __syncthreads();

  f32x4 oacc[3][2];
  uint32_t qrow = st * 16u + l15; if (qrow > 48u) qrow = 48u;
  const uint32_t w6 = win & 63u;

  #pragma unroll
  for (uint32_t hl = 0; hl < 3u; ++hl) {
    uint32_t h = grp * 3u + hl;
    bf16x8 qb = *(const bf16x8*)(qo + (wrow0 + qrow) * CDIM + h * 32u + lg * 8u);
    f32x4 s[4];
    #pragma unroll
    for (uint32_t nt = 0; nt < 4u; ++nt) {
      uint32_t krow = nt * 16u + l15; if (krow > 48u) krow = 48u;
      bf16x8 ka = *(const bf16x8*)(kbf + (wrow0 + krow) * CDIM + h * 32u + lg * 8u);
      f32x4 z = {};
      s[nt] = __builtin_amdgcn_mfma_f32_16x16x32_bf16(ka, qb, z, 0, 0, 0);
    }
    const bf16* bp = b5L + ((((w6 * 6u + h) * 16u) + st * 4u) << 8) + lane * 4u;
    #pragma unroll
    for (uint32_t nt = 0; nt < 4u; ++nt) {
      uint2 bv = *(const uint2*)(bp + nt * 256u);
      s[nt][0] += bfu2f(bv.x);
      s[nt][1] += bfh2f(bv.x);
      s[nt][2] += bfu2f(bv.y);
      s[nt][3] += bfh2f(bv.y);
    }
    float mm = s[0][0];
    #pragma unroll
    for (uint32_t nt = 0; nt < 4u; ++nt)
      #pragma unroll
      for (uint32_t r = 0; r < 4u; ++r) mm = fmaxf(mm, s[nt][r]);
    mm = fmaxf(mm, __shfl_xor(mm, 16)); mm = fmaxf(mm, __shfl_xor(mm, 32));
    float ss = 0.f;
    #pragma unroll
    for (uint32_t nt = 0; nt < 4u; ++nt)
      #pragma unroll
      for (uint32_t r = 0; r < 4u; ++r) { float p = __expf(s[nt][r] - mm); s[nt][r] = p; ss += p; }
    ss += __shfl_xor(ss, 16); ss += __shfl_xor(ss, 32);
    float inv = 1.f / ss;
    #pragma unroll
    for (uint32_t nt = 0; nt < 4u; ++nt) {
      uint2 w;
      w.x = (f2u(s[nt][1] * inv) << 16) | f2u(s[nt][0] * inv);
      w.y = (f2u(s[nt][3] * inv) << 16) | f2u(s[nt][2] * inv);
      *(uint2*)(strip + l15 * 144u + nt * 32u + lg * 8u) = w;
    }
    bf16x8 pb0 = *(const bf16x8*)(strip + l15 * 144u + lg * 16u);
    bf16x8 pb1 = *(const bf16x8*)(strip + l15 * 144u + 64u + lg * 16u);
    #pragma unroll
    for (uint32_t nt2 = 0; nt2 < 2u; ++nt2) {
      uint32_t ch = h * 32u + nt2 * 16u + l15;
      uint32_t va = voff(ch);
      bf16x8 va0 = *(const bf16x8*)(lds + va + lg * 16u);
      bf16x8 va1 = *(const bf16x8*)(lds + va + 64u + lg * 16u);
      f32x4 z = {};
      f32x4 o = __builtin_amdgcn_mfma_f32_16x16x32_bf16(va0, pb0, z, 0, 0, 0);
      oacc[hl][nt2] = __builtin_amdgcn_mfma_f32_16x16x32_bf16(va1, pb1, o, 0, 0, 0);
    }
  }

  __syncthreads();   // all VT/strip reads done -> reuse VT region as O tile

  {
    uint32_t orow = (st * 16u + l15) * OSTRIDE;
    #pragma unroll
    for (uint32_t hl = 0; hl < 3u; ++hl)
      #pragma unroll
      for (uint32_t nt2 = 0; nt2 < 2u; ++nt2) {
        uint32_t d0 = (grp * 3u + hl) * 32u + nt2 * 16u + lg * 4u;
        uint2 w;
        w.x = (f2u(oacc[hl][nt2][1]) << 16) | f2u(oacc[hl][nt2][0]);
        w.y = (f2u(oacc[hl][nt2][3]) << 16) | f2u(oacc[hl][nt2][2]);
        *(uint2*)(lds + orow + d0 * 2u) = w;
      }
  }

  __syncthreads();   // O tile ready -> fused proj

  {
    const uint32_t st2 = (wv & 3u) * 16u;        // row strip
    const uint32_t colbase = (wv >> 2) * 96u;    // output-channel half
    bf16x8 paf[6];
    #pragma unroll
    for (uint32_t kk = 0; kk < 6u; ++kk)
      paf[kk] = *(const bf16x8*)(lds + (st2 + l15) * OSTRIDE + kk * 64u + lg * 16u);
    f32x4 pacc[6] = {};
    #pragma unroll
    for (uint32_t kk = 0; kk < 6u; ++kk)
      #pragma unroll
      for (uint32_t ntl = 0; ntl < 6u; ++ntl) {
        bf16x8 wb = *(const bf16x8*)(wproj_bf + (colbase + ntl * 16u + l15) * CDIM + kk * 32u + lg * 8u);
        pacc[ntl] = __builtin_amdgcn_mfma_f32_16x16x32_bf16(paf[kk], wb, pacc[ntl], 0, 0, 0);
      }
    #pragma unroll
    for (uint32_t ntl = 0; ntl < 6u; ++ntl) {
      uint32_t ch = colbase + ntl * 16u + l15;
      float bias = bproj[ch];
      #pragma unroll
      for (uint32_t r = 0; r < 4u; ++r) {
        uint32_t row = st2 + lg * 4u + r;
        if (row < NTOK)
          out[(wrow0 + row) * CDIM + ch] = pacc[ntl][r] + bias;
      }
    }
  }
}

extern "C" void kernel_launch(void* const* d_in, const int* in_sizes, int n_in,
                              void* d_out, int out_size, void* d_ws, size_t ws_size,
                              hipStream_t stream) {
  const float* x     = (const float*)d_in[0];
  const float* skip  = (const float*)d_in[1];
  const float* mask  = (const float*)d_in[2];
  const int*   rpi   = (const int*)  d_in[3];
  const float* rpb   = (const float*)d_in[4];
  const float* wqkv  = (const float*)d_in[5];
  const float* bqkv  = (const float*)d_in[6];
  const float* wskip = (const float*)d_in[7];
  const float* bskip = (const float*)d_in[8];
  const float* wproj = (const float*)d_in[9];
  const float* bproj = (const float*)d_in[10];

  char* ws = (char*)d_ws;
  bf16* wbf  = (bf16*)(ws + WSB_W);
  bf16* b5L  = (bf16*)(ws + WSB_B5);
  bf16* qo   = (bf16*)(ws + WSB_QO);
  bf16* kbf  = (bf16*)(ws + WSB_K);
  bf16* vbf  = (bf16*)(ws + WSB_V);

  uint32_t nwin  = (uint32_t)(in_sizes[0] / (NTOK * CDIM));
  uint32_t nrows = nwin * NTOK;            // 200704, divisible by 64
  uint32_t ngb   = nrows / 64u;

  hipFuncSetAttribute((const void*)qkv_kernel,  hipFuncAttributeMaxDynamicSharedMemorySize, (int)QKV_LDS);
  hipFuncSetAttribute((const void*)attn_kernel, hipFuncAttributeMaxDynamicSharedMemorySize, (int)ATTN_LDS);

  wcvt_kernel<<<144, 256, 0, stream>>>(wqkv, wskip, wproj, wbf);
  biasprep_kernel<<<6144, 256, 0, stream>>>(rpi, rpb, mask, b5L);
  qkv_kernel<<<ngb, 256, QKV_LDS, stream>>>(skip, x, wbf, bskip, bqkv, qo, kbf, vbf);
  attn_kernel<<<nwin, 512, ATTN_LDS, stream>>>(qo, kbf, vbf, b5L,
                                               wbf + WSE_WPROJ, bproj, (float*)d_out);
}

// Round 11
// 326.727 us; speedup vs baseline: 1.2632x; 1.2632x over previous
//
#include <hip/hip_runtime.h>
#include <hip/hip_bf16.h>
#include <stdint.h>

// WindowMSA, round 11:
//  - r10 post-mortem: fused proj's per-lane scattered global W reads (16 lines
//    per instr) serialized the attn kernel. Fix: wcvt also emits wproj in
//    MFMA-B-fragment order (wpf) -> proj B-frag loads are 1KB coalesced/wave.
//  - qkv: M=64 -> 128 (512 thr): same 36KB W stage feeds 2x rows -> half the
//    W staging work and L2 traffic, fewer barriers per row.
// attn QK^T/softmax/PV identical to round 9/10 (double-swapped MFMA).

typedef __bf16 bf16;
typedef __attribute__((ext_vector_type(8))) __bf16 bf16x8;
typedef __attribute__((ext_vector_type(4))) float f32x4;

#define CDIM 192
#define NH 6
#define NTOK 49
#define QSCALE 0.17677669529663687f

// ws byte offsets
#define WSB_W      0u          // 147456 bf16 = 294912 B (wqkv | wskip | wproj)
#define WSE_WSKIP  73728u
#define WSB_WPF    294912u     // wproj fragment-ordered: 36864 bf16 = 73728 B
#define WSB_B5     368640u     // b5L: 64*6*16*256 bf16 = 3,145,728 B
#define WSB_QO     3514368u    // 200704*192 bf16 = 77,070,336 B
#define WSB_K      80584704u
#define WSB_V      157655040u  // end 234,725,376

// qkv kernel LDS: 96-row W stage (36864 B); transpose tile reuses first 26624 B
#define QKV_LDS  36864u
#define QTSTRIDE 208u

// attn LDS: VT region 27904 (voff(191)+128 = 27808), 8 strips of 2304
#define OFF_STRIP 27904u
#define STRIPB    2304u
#define ATTN_LDS  46336u       // 27904 + 8*2304
#define OSTRIDE   400u         // O tile row stride (reuses VT region)

__device__ __forceinline__ uint32_t swz384(uint32_t row, uint32_t b) {
  return row * 384u + (b ^ ((row & 7u) << 4));
}
__device__ __forceinline__ uint32_t voff(uint32_t ch) {   // VT row base, 16B-aligned, monotone
  return ch * 144u + ((ch >> 4) << 4);
}
__device__ __forceinline__ uint32_t f2u(float f) { bf16 h = (bf16)f; return (uint32_t)__builtin_bit_cast(uint16_t, h); }
__device__ __forceinline__ bf16x8 lda8(const float* p) {
  float4 w0 = *(const float4*)p;
  float4 w1 = *(const float4*)(p + 4);
  bf16x8 b = {(bf16)w0.x, (bf16)w0.y, (bf16)w0.z, (bf16)w0.w,
              (bf16)w1.x, (bf16)w1.y, (bf16)w1.z, (bf16)w1.w};
  return b;
}
__device__ __forceinline__ float bfu2f(uint32_t lo16) { return __builtin_bit_cast(float, lo16 << 16); }
__device__ __forceinline__ float bfh2f(uint32_t hi16) { return __builtin_bit_cast(float, hi16 & 0xffff0000u); }

// ---- weights f32 -> bf16 (plus wproj fragment-ordered copy) ----
__global__ void __launch_bounds__(256)
wcvt_kernel(const float* __restrict__ wqkv, const float* __restrict__ wskip,
            const float* __restrict__ wproj, bf16* __restrict__ ws,
            bf16* __restrict__ wpf) {
  uint32_t i4 = blockIdx.x * 256u + threadIdx.x;
  uint32_t i = i4 * 4u;
  if (i < 147456u) {
    float4 v;
    if (i < 73728u)       v = *(const float4*)(wqkv + i);
    else if (i < 110592u) v = *(const float4*)(wskip + (i - 73728u));
    else                  v = *(const float4*)(wproj + (i - 110592u));
    *(uint2*)(ws + i) = make_uint2((f2u(v.y) << 16) | f2u(v.x), (f2u(v.w) << 16) | f2u(v.z));
  } else if (i < 184320u) {
    // fragment-ordered wproj: wpf[((ntl*6+kk)*64+lane)*8+j] = wproj[ntl*16+(lane&15)][kk*32+(lane>>4)*8+j]
    uint32_t f4 = i4 - 36864u;              // [0, 9216)
    uint32_t j0 = (f4 & 1u) * 4u;
    uint32_t lane = (f4 >> 1) & 63u;
    uint32_t kkntl = f4 >> 7;               // [0, 72)
    uint32_t kk = kkntl % 6u, ntl = kkntl / 6u;
    uint32_t row = ntl * 16u + (lane & 15u);
    uint32_t col = kk * 32u + (lane >> 4) * 8u + j0;
    float4 v = *(const float4*)(wproj + row * CDIM + col);
    *(uint2*)(wpf + (i - 147456u)) =
        make_uint2((f2u(v.y) << 16) | f2u(v.x), (f2u(v.w) << 16) | f2u(v.z));
  }
}

// ---- bias for transposed S: t = (((w*6+h)*16 + st*4+nt)*64 + lane)*4 + r
//      i (query) = st*16 + (lane&15) ; j (key) = nt*16 + (lane>>4)*4 + r ----
__global__ void __launch_bounds__(256)
biasprep_kernel(const int* __restrict__ rpi, const float* __restrict__ rpb,
                const float* __restrict__ mask, bf16* __restrict__ b5) {
  uint32_t t = blockIdx.x * 256u + threadIdx.x;
  if (t >= 1572864u) return;
  uint32_t w    = t / 24576u;
  uint32_t rem  = t - w * 24576u;
  uint32_t h    = rem / 4096u;
  uint32_t rem2 = rem & 4095u;
  uint32_t stnt = rem2 >> 8, lane = (rem2 >> 2) & 63u, r = rem2 & 3u;
  uint32_t i = (stnt >> 2) * 16u + (lane & 15u);
  uint32_t j = (stnt & 3u) * 16u + (lane >> 4) * 4u + r;
  float v;
  if (j >= NTOK)      v = -1e30f;      // key-pad: softmax weight -> 0
  else if (i >= NTOK) v = 0.f;         // query-pad rows are never stored
  else v = rpb[(uint32_t)rpi[i * NTOK + j] * NH + h] + mask[(size_t)w * (NTOK * NTOK) + i * NTOK + j];
  b5[t] = (bf16)v;
}

// ---- fused QKV GEMM: 6 half-W phases, M=128/block, 512 thr ----
__global__ void __launch_bounds__(512, 4)
qkv_kernel(const float* __restrict__ skip, const float* __restrict__ x,
           const bf16* __restrict__ wbf, const float* __restrict__ bskip,
           const float* __restrict__ bqkv, bf16* __restrict__ qo,
           bf16* __restrict__ kbf, bf16* __restrict__ vbf) {
  extern __shared__ char lds[];
  const uint32_t tid = threadIdx.x, lane = tid & 63u, wv = tid >> 6;  // 8 waves
  const uint32_t l15 = lane & 15u, lg = lane >> 4;
  const uint32_t rowbase = blockIdx.x * 128u;
  const uint32_t arow = rowbase + wv * 16u + l15;

  bf16x8 af[6];
  #pragma unroll
  for (uint32_t p = 0; p < 6u; ++p) {
    if (p == 0u || p == 2u) {
      const float* ap = (p ? x : skip) + (size_t)arow * CDIM + lg * 8u;
      #pragma unroll
      for (uint32_t kk = 0; kk < 6u; ++kk) af[kk] = lda8(ap + kk * 32u);
    }
    if (p) __syncthreads();            // previous copy-out done
    // stage 96 W rows, swizzled
    const bf16* wsrc = wbf + (p < 2u ? WSE_WSKIP + (p & 1u) * 18432u
                                     : (p - 2u) * 18432u);
    for (uint32_t u = tid; u < 2304u; u += 512u) {       // 96 rows x 24 uint4
      uint32_t row = u / 24u, c16 = u - row * 24u;
      uint4 v = *(const uint4*)(wsrc + row * 192u + c16 * 8u);
      *(uint4*)(lds + row * 384u + ((c16 * 16u) ^ ((row & 7u) << 4))) = v;
    }
    __syncthreads();
    f32x4 acc[6] = {};
    #pragma unroll
    for (uint32_t kk = 0; kk < 6u; ++kk)
      #pragma unroll
      for (uint32_t ntl = 0; ntl < 6u; ++ntl) {
        bf16x8 wb = *(const bf16x8*)(lds + swz384(ntl * 16u + l15, kk * 64u + lg * 16u));
        acc[ntl] = __builtin_amdgcn_mfma_f32_16x16x32_bf16(af[kk], wb, acc[ntl], 0, 0, 0);
      }
    __syncthreads();                   // W reads done -> reuse as transpose tile
    const float* bias_base = (p < 2u) ? bskip + (p & 1u) * 96u
                                      : bqkv + (p - 2u) * 96u;
    const float scale = (p < 2u) ? QSCALE : 1.0f;
    #pragma unroll
    for (uint32_t ntl = 0; ntl < 6u; ++ntl) {
      float bias = bias_base[ntl * 16u + l15];
      #pragma unroll
      for (uint32_t r = 0; r < 4u; ++r) {
        uint32_t trow = wv * 16u + lg * 4u + r;          // 0..127
        *(bf16*)(lds + trow * QTSTRIDE + (ntl * 16u + l15) * 2u) =
            (bf16)((acc[ntl][r] + bias) * scale);
      }
    }
    __syncthreads();                   // transpose tile ready
    bf16* dst = (p < 2u) ? qo : ((p < 4u) ? kbf : vbf);
    const uint32_t colofs = (p & 1u) * 96u;
    for (uint32_t i = tid; i < 1536u; i += 512u) {       // 128 rows x 12 uint4
      uint32_t row = i / 12u, c16 = i - row * 12u;
      uint4 v = *(const uint4*)(lds + row * QTSTRIDE + c16 * 16u);
      *(uint4*)(dst + (size_t)(rowbase + row) * CDIM + colofs + c16 * 8u) = v;
    }
  }
}

// ---- attention + proj: one block per window, 512 thr ----
__global__ void __launch_bounds__(512, 6)
attn_kernel(const bf16* __restrict__ qo, const bf16* __restrict__ kbf,
            const bf16* __restrict__ vbf, const bf16* __restrict__ b5L,
            const bf16* __restrict__ wpf, const float* __restrict__ bproj,
            float* __restrict__ out) {
  extern __shared__ char lds[];
  const uint32_t tid = threadIdx.x, lane = tid & 63u, wv = tid >> 6;
  const uint32_t l15 = lane & 15u, lg = lane >> 4;
  const uint32_t grp = wv >> 2, st = wv & 3u;
  const uint32_t win = blockIdx.x;
  char* strip = lds + OFF_STRIP + wv * STRIPB;
  const size_t wrow0 = (size_t)win * NTOK;

  // ---- stage V transposed, tok-pair packed b32 writes ----
  for (uint32_t i = tid; i < 600u; i += 512u) {          // 25 pairs x 24 c16
    uint32_t pair = i / 24u, c16 = i - pair * 24u;
    uint32_t tok0 = pair * 2u;                           // 0,2,..,48
    const bf16* src = vbf + (wrow0 + tok0) * CDIM + c16 * 8u;
    uint4 a = *(const uint4*)src;
    uint4 b = make_uint4(0u, 0u, 0u, 0u);
    if (tok0 + 1u < NTOK) b = *(const uint4*)(src + CDIM);
    uint32_t base = voff(c16 * 8u) + tok0 * 2u;
    uint32_t aw[4] = {a.x, a.y, a.z, a.w};
    uint32_t bw[4] = {b.x, b.y, b.z, b.w};
    #pragma unroll
    for (uint32_t q = 0; q < 4u; ++q) {
      *(uint32_t*)(lds + base + (2u * q) * 144u)      = (aw[q] & 0xffffu) | (bw[q] << 16);
      *(uint32_t*)(lds + base + (2u * q + 1u) * 144u) = (aw[q] >> 16) | (bw[q] & 0xffff0000u);
    }
  }
  for (uint32_t i = tid; i < 1344u; i += 512u) {         // zero toks 50..63
    uint32_t ch = i / 7u, p = i - ch * 7u;
    *(uint32_t*)(lds + voff(ch) + (50u + p * 2u) * 2u) = 0u;
  }
  __syncthreads();

  f32x4 oacc[3][2];
  uint32_t qrow = st * 16u + l15; if (qrow > 48u) qrow = 48u;
  const uint32_t w6 = win & 63u;

  #pragma unroll
  for (uint32_t hl = 0; hl < 3u; ++hl) {
    uint32_t h = grp * 3u + hl;
    bf16x8 qb = *(const bf16x8*)(qo + (wrow0 + qrow) * CDIM + h * 32u + lg * 8u);
    f32x4 s[4];
    #pragma unroll
    for (uint32_t nt = 0; nt < 4u; ++nt) {
      uint32_t krow = nt * 16u + l15; if (krow > 48u) krow = 48u;
      bf16x8 ka = *(const bf16x8*)(kbf + (wrow0 + krow) * CDIM + h * 32u + lg * 8u);
      f32x4 z = {};
      s[nt] = __builtin_amdgcn_mfma_f32_16x16x32_bf16(ka, qb, z, 0, 0, 0);
    }
    const bf16* bp = b5L + ((((w6 * 6u + h) * 16u) + st * 4u) << 8) + lane * 4u;
    #pragma unroll
    for (uint32_t nt = 0; nt < 4u; ++nt) {
      uint2 bv = *(const uint2*)(bp + nt * 256u);
      s[nt][0] += bfu2f(bv.x);
      s[nt][1] += bfh2f(bv.x);
      s[nt][2] += bfu2f(bv.y);
      s[nt][3] += bfh2f(bv.y);
    }
    float mm = s[0][0];
    #pragma unroll
    for (uint32_t nt = 0; nt < 4u; ++nt)
      #pragma unroll
      for (uint32_t r = 0; r < 4u; ++r) mm = fmaxf(mm, s[nt][r]);
    mm = fmaxf(mm, __shfl_xor(mm, 16)); mm = fmaxf(mm, __shfl_xor(mm, 32));
    float ss = 0.f;
    #pragma unroll
    for (uint32_t nt = 0; nt < 4u; ++nt)
      #pragma unroll
      for (uint32_t r = 0; r < 4u; ++r) { float p = __expf(s[nt][r] - mm); s[nt][r] = p; ss += p; }
    ss += __shfl_xor(ss, 16); ss += __shfl_xor(ss, 32);
    float inv = 1.f / ss;
    #pragma unroll
    for (uint32_t nt = 0; nt < 4u; ++nt) {
      uint2 w;
      w.x = (f2u(s[nt][1] * inv) << 16) | f2u(s[nt][0] * inv);
      w.y = (f2u(s[nt][3] * inv) << 16) | f2u(s[nt][2] * inv);
      *(uint2*)(strip + l15 * 144u + nt * 32u + lg * 8u) = w;
    }
    bf16x8 pb0 = *(const bf16x8*)(strip + l15 * 144u + lg * 16u);
    bf16x8 pb1 = *(const bf16x8*)(strip + l15 * 144u + 64u + lg * 16u);
    #pragma unroll
    for (uint32_t nt2 = 0; nt2 < 2u; ++nt2) {
      uint32_t ch = h * 32u + nt2 * 16u + l15;
      uint32_t va = voff(ch);
      bf16x8 va0 = *(const bf16x8*)(lds + va + lg * 16u);
      bf16x8 va1 = *(const bf16x8*)(lds + va + 64u + lg * 16u);
      f32x4 z = {};
      f32x4 o = __builtin_amdgcn_mfma_f32_16x16x32_bf16(va0, pb0, z, 0, 0, 0);
      oacc[hl][nt2] = __builtin_amdgcn_mfma_f32_16x16x32_bf16(va1, pb1, o, 0, 0, 0);
    }
  }

  __syncthreads();   // all VT/strip reads done -> reuse VT region as O tile

  {
    uint32_t orow = (st * 16u + l15) * OSTRIDE;
    #pragma unroll
    for (uint32_t hl = 0; hl < 3u; ++hl)
      #pragma unroll
      for (uint32_t nt2 = 0; nt2 < 2u; ++nt2) {
        uint32_t d0 = (grp * 3u + hl) * 32u + nt2 * 16u + lg * 4u;
        uint2 w;
        w.x = (f2u(oacc[hl][nt2][1]) << 16) | f2u(oacc[hl][nt2][0]);
        w.y = (f2u(oacc[hl][nt2][3]) << 16) | f2u(oacc[hl][nt2][2]);
        *(uint2*)(lds + orow + d0 * 2u) = w;
      }
  }

  __syncthreads();   // O tile ready -> fused proj (fragment-ordered W, coalesced)

  {
    const uint32_t st2 = (wv & 3u) * 16u;        // row strip
    const uint32_t ntlg0 = (wv >> 2) * 6u;       // output-channel half: tiles 0..5 / 6..11
    bf16x8 paf[6];
    #pragma unroll
    for (uint32_t kk = 0; kk < 6u; ++kk)
      paf[kk] = *(const bf16x8*)(lds + (st2 + l15) * OSTRIDE + kk * 64u + lg * 16u);
    f32x4 pacc[6] = {};
    #pragma unroll
    for (uint32_t kk = 0; kk < 6u; ++kk)
      #pragma unroll
      for (uint32_t ntl = 0; ntl < 6u; ++ntl) {
        bf16x8 wb = *(const bf16x8*)(wpf + (((ntlg0 + ntl) * 6u + kk) * 64u + lane) * 8u);
        pacc[ntl] = __builtin_amdgcn_mfma_f32_16x16x32_bf16(paf[kk], wb, pacc[ntl], 0, 0, 0);
      }
    #pragma unroll
    for (uint32_t ntl = 0; ntl < 6u; ++ntl) {
      uint32_t ch = (ntlg0 + ntl) * 16u + l15;
      float bias = bproj[ch];
      #pragma unroll
      for (uint32_t r = 0; r < 4u; ++r) {
        uint32_t row = st2 + lg * 4u + r;
        if (row < NTOK)
          out[(wrow0 + row) * CDIM + ch] = pacc[ntl][r] + bias;
      }
    }
  }
}

extern "C" void kernel_launch(void* const* d_in, const int* in_sizes, int n_in,
                              void* d_out, int out_size, void* d_ws, size_t ws_size,
                              hipStream_t stream) {
  const float* x     = (const float*)d_in[0];
  const float* skip  = (const float*)d_in[1];
  const float* mask  = (const float*)d_in[2];
  const int*   rpi   = (const int*)  d_in[3];
  const float* rpb   = (const float*)d_in[4];
  const float* wqkv  = (const float*)d_in[5];
  const float* bqkv  = (const float*)d_in[6];
  const float* wskip = (const float*)d_in[7];
  const float* bskip = (const float*)d_in[8];
  const float* wproj = (const float*)d_in[9];
  const float* bproj = (const float*)d_in[10];

  char* ws = (char*)d_ws;
  bf16* wbf  = (bf16*)(ws + WSB_W);
  bf16* wpf  = (bf16*)(ws + WSB_WPF);
  bf16* b5L  = (bf16*)(ws + WSB_B5);
  bf16* qo   = (bf16*)(ws + WSB_QO);
  bf16* kbf  = (bf16*)(ws + WSB_K);
  bf16* vbf  = (bf16*)(ws + WSB_V);

  uint32_t nwin  = (uint32_t)(in_sizes[0] / (NTOK * CDIM));
  uint32_t nrows = nwin * NTOK;            // 200704, divisible by 128
  uint32_t ngb   = nrows / 128u;

  hipFuncSetAttribute((const void*)qkv_kernel,  hipFuncAttributeMaxDynamicSharedMemorySize, (int)QKV_LDS);
  hipFuncSetAttribute((const void*)attn_kernel, hipFuncAttributeMaxDynamicSharedMemorySize, (int)ATTN_LDS);

  wcvt_kernel<<<180, 256, 0, stream>>>(wqkv, wskip, wproj, wbf, wpf);
  biasprep_kernel<<<6144, 256, 0, stream>>>(rpi, rpb, mask, b5L);
  qkv_kernel<<<ngb, 512, QKV_LDS, stream>>>(skip, x, wbf, bskip, bqkv, qo, kbf, vbf);
  attn_kernel<<<nwin, 512, ATTN_LDS, stream>>>(qo, kbf, vbf, b5L, wpf, bproj, (float*)d_out);
}